// Round 7
// baseline (167.524 us; speedup 1.0000x reference)
//
#include <hip/hip_runtime.h>
#include <math.h>

// Problem constants (match reference).
#define BDIM 4096
#define TDIM 2048
#define NBLK 512          // k1 grid: BDIM / RPB  (partial stays [512][2048] = 4 MB)
#define RPB  8            // rows per k1 block (processed as 4 pairs, 2-row ILP)

// gamma powers as exact compile-time folded constants
constexpr double gpow(int e) {
    double r = 1.0;
    for (int i = 0; i < e; ++i) r *= 0.99;
    return r;
}

__device__ __forceinline__ float logsig_fast(float x) {
    // log(sigmoid(x)) = min(x,0) - log(1 + exp(-|x|)); HW transcendentals.
    float z = __expf(-fabsf(x));
    return fminf(x, 0.0f) - __logf(1.0f + z);
}

__device__ __forceinline__ float clip5(float x) {
    return fminf(fmaxf(x, -5.0f), 5.0f);
}

// ---------------------------------------------------------------------------
// K1: per-row reverse discounted scan (c[t] = wr[t] + g*c[t+1]); writes cum
// and per-block column partials. 2-row ILP: rows are independent scans, so
// each iteration runs TWO interleaved shuffle chains (latency shared) and
// pays ONE barrier per pair (4 total vs 8). Blocks 0/1 zero colsum/obj.
// ---------------------------------------------------------------------------
__global__ __launch_bounds__(256) void k1_scan(
    const float* __restrict__ logits,
    const float* __restrict__ weight,
    const float* __restrict__ baselines,
    float* __restrict__ cum_out,
    float* __restrict__ partial,
    float* __restrict__ colsum,
    float* __restrict__ obj)
{
    const int tid  = threadIdx.x;
    const int lane = tid & 63;
    const int wave = tid >> 6;
    const int t0   = tid * 8;          // 8 contiguous columns per thread

    // in-kernel zeroing (k2/k3/k4 are stream-ordered after k1)
    if (blockIdx.x == 0) {
        *reinterpret_cast<float4*>(colsum + t0)     = make_float4(0.f, 0.f, 0.f, 0.f);
        *reinterpret_cast<float4*>(colsum + t0 + 4) = make_float4(0.f, 0.f, 0.f, 0.f);
    }
    if (blockIdx.x == 1) {
        *reinterpret_cast<float4*>(obj + t0)     = make_float4(0.f, 0.f, 0.f, 0.f);
        *reinterpret_cast<float4*>(obj + t0 + 4) = make_float4(0.f, 0.f, 0.f, 0.f);
    }

    const float G    = 0.99f;
    const float G512 = (float)gpow(512);
    const float LOG2G = -0.014499569695115089f;  // log2(0.99)
    const float gk[8] = {(float)gpow(8), (float)gpow(7), (float)gpow(6), (float)gpow(5),
                         (float)gpow(4), (float)gpow(3), (float)gpow(2), (float)gpow(1)};
    // shuffle-scan factors gamma^(8*2^s) as compile-time constants
    const float fs[6] = {(float)gpow(8),  (float)gpow(16), (float)gpow(32),
                         (float)gpow(64), (float)gpow(128), (float)gpow(256)};
    const float lane_pow = exp2f((float)((64 - lane) * 8) * LOG2G);

    __shared__ float wsum[2][2][4];   // [iter parity][row in pair][wave]

    float colacc[8];
#pragma unroll
    for (int k = 0; k < 8; ++k) colacc[k] = 0.0f;

    const int row0 = blockIdx.x * RPB;
    size_t baseA = (size_t)row0 * TDIM + t0;   // row 2*it
    // row B base = baseA + TDIM

    // preload pair 0 (rows 0,1)
    float4 xa0 = *reinterpret_cast<const float4*>(logits + baseA);
    float4 xa1 = *reinterpret_cast<const float4*>(logits + baseA + 4);
    float4 wa0 = *reinterpret_cast<const float4*>(weight + baseA);
    float4 wa1 = *reinterpret_cast<const float4*>(weight + baseA + 4);
    float4 ba0 = *reinterpret_cast<const float4*>(baselines + baseA);
    float4 ba1 = *reinterpret_cast<const float4*>(baselines + baseA + 4);
    float4 xb0 = *reinterpret_cast<const float4*>(logits + baseA + TDIM);
    float4 xb1 = *reinterpret_cast<const float4*>(logits + baseA + TDIM + 4);
    float4 wb0 = *reinterpret_cast<const float4*>(weight + baseA + TDIM);
    float4 wb1 = *reinterpret_cast<const float4*>(weight + baseA + TDIM + 4);
    float4 bb0 = *reinterpret_cast<const float4*>(baselines + baseA + TDIM);
    float4 bb1 = *reinterpret_cast<const float4*>(baselines + baseA + TDIM + 4);

#pragma unroll
    for (int it = 0; it < RPB / 2; ++it) {
        const size_t nbase = baseA + 2 * TDIM;     // next pair's row A
        const bool has_next = (it + 1 < RPB / 2);

        float wrA[8], wrB[8];
        wrA[0] = wa0.x * logsig_fast(xa0.x); wrA[1] = wa0.y * logsig_fast(xa0.y);
        wrA[2] = wa0.z * logsig_fast(xa0.z); wrA[3] = wa0.w * logsig_fast(xa0.w);
        wrA[4] = wa1.x * logsig_fast(xa1.x); wrA[5] = wa1.y * logsig_fast(xa1.y);
        wrA[6] = wa1.z * logsig_fast(xa1.z); wrA[7] = wa1.w * logsig_fast(xa1.w);
        wrB[0] = wb0.x * logsig_fast(xb0.x); wrB[1] = wb0.y * logsig_fast(xb0.y);
        wrB[2] = wb0.z * logsig_fast(xb0.z); wrB[3] = wb0.w * logsig_fast(xb0.w);
        wrB[4] = wb1.x * logsig_fast(xb1.x); wrB[5] = wb1.y * logsig_fast(xb1.y);
        wrB[6] = wb1.z * logsig_fast(xb1.z); wrB[7] = wb1.w * logsig_fast(xb1.w);

        // prefetch next pair: latency hides under the two scan chains below
        float4 nxa0, nxa1, nwa0, nwa1, nba0, nba1;
        float4 nxb0, nxb1, nwb0, nwb1, nbb0, nbb1;
        if (has_next) {
            nxa0 = *reinterpret_cast<const float4*>(logits + nbase);
            nxa1 = *reinterpret_cast<const float4*>(logits + nbase + 4);
            nwa0 = *reinterpret_cast<const float4*>(weight + nbase);
            nwa1 = *reinterpret_cast<const float4*>(weight + nbase + 4);
            nba0 = *reinterpret_cast<const float4*>(baselines + nbase);
            nba1 = *reinterpret_cast<const float4*>(baselines + nbase + 4);
            nxb0 = *reinterpret_cast<const float4*>(logits + nbase + TDIM);
            nxb1 = *reinterpret_cast<const float4*>(logits + nbase + TDIM + 4);
            nwb0 = *reinterpret_cast<const float4*>(weight + nbase + TDIM);
            nwb1 = *reinterpret_cast<const float4*>(weight + nbase + TDIM + 4);
            nbb0 = *reinterpret_cast<const float4*>(baselines + nbase + TDIM);
            nbb1 = *reinterpret_cast<const float4*>(baselines + nbase + TDIM + 4);
        }

        // local suffix scans (independent chains, compiler interleaves)
        float locA[8], locB[8];
        locA[7] = wrA[7]; locB[7] = wrB[7];
#pragma unroll
        for (int k = 6; k >= 0; --k) {
            locA[k] = fmaf(G, locA[k + 1], wrA[k]);
            locB[k] = fmaf(G, locB[k + 1], wrB[k]);
        }

        // wave-level weighted suffix scan — TWO interleaved shuffle chains
        float vA = locA[0], vB = locB[0];
#pragma unroll
        for (int s = 0; s < 6; ++s) {
            const int o = 1 << s;
            float upA = __shfl_down(vA, (unsigned)o, 64);
            float upB = __shfl_down(vB, (unsigned)o, 64);
            if (lane + o < 64) {
                vA = fmaf(fs[s], upA, vA);
                vB = fmaf(fs[s], upB, vB);
            }
        }

        // cross-wave carries via LDS — ONE barrier per pair (double-buffered)
        const int buf = it & 1;
        if (lane == 0) { wsum[buf][0][wave] = vA; wsum[buf][1][wave] = vB; }
        __syncthreads();
        const float A1 = wsum[buf][0][1], A2 = wsum[buf][0][2], A3 = wsum[buf][0][3];
        const float B1 = wsum[buf][1][1], B2 = wsum[buf][1][2], B3 = wsum[buf][1][3];
        const float FA3 = A3;
        const float FA2 = fmaf(G512, FA3, A2);
        const float FA1 = fmaf(G512, FA2, A1);
        const float FB3 = B3;
        const float FB2 = fmaf(G512, FB3, B2);
        const float FB1 = fmaf(G512, FB2, B1);
        const float carryA = (wave == 0) ? FA1 : (wave == 1) ? FA2 : (wave == 2) ? FA3 : 0.0f;
        const float carryB = (wave == 0) ? FB1 : (wave == 1) ? FB2 : (wave == 2) ? FB3 : 0.0f;

        const float vfullA = fmaf(lane_pow, carryA, vA);
        const float vfullB = fmaf(lane_pow, carryB, vB);
        const float vnA = __shfl_down(vfullA, 1, 64);
        const float vnB = __shfl_down(vfullB, 1, 64);
        const float tailA = (lane == 63) ? carryA : vnA;
        const float tailB = (lane == 63) ? carryB : vnB;

        float cA[8], cB[8];
#pragma unroll
        for (int k = 0; k < 8; ++k) {
            cA[k] = fmaf(gk[k], tailA, locA[k]);
            cB[k] = fmaf(gk[k], tailB, locB[k]);
        }

        *reinterpret_cast<float4*>(cum_out + baseA)            = make_float4(cA[0], cA[1], cA[2], cA[3]);
        *reinterpret_cast<float4*>(cum_out + baseA + 4)        = make_float4(cA[4], cA[5], cA[6], cA[7]);
        *reinterpret_cast<float4*>(cum_out + baseA + TDIM)     = make_float4(cB[0], cB[1], cB[2], cB[3]);
        *reinterpret_cast<float4*>(cum_out + baseA + TDIM + 4) = make_float4(cB[4], cB[5], cB[6], cB[7]);

        colacc[0] += (cA[0] - ba0.x) + (cB[0] - bb0.x);
        colacc[1] += (cA[1] - ba0.y) + (cB[1] - bb0.y);
        colacc[2] += (cA[2] - ba0.z) + (cB[2] - bb0.z);
        colacc[3] += (cA[3] - ba0.w) + (cB[3] - bb0.w);
        colacc[4] += (cA[4] - ba1.x) + (cB[4] - bb1.x);
        colacc[5] += (cA[5] - ba1.y) + (cB[5] - bb1.y);
        colacc[6] += (cA[6] - ba1.z) + (cB[6] - bb1.z);
        colacc[7] += (cA[7] - ba1.w) + (cB[7] - bb1.w);

        baseA = nbase;
        if (has_next) {
            xa0 = nxa0; xa1 = nxa1; wa0 = nwa0; wa1 = nwa1; ba0 = nba0; ba1 = nba1;
            xb0 = nxb0; xb1 = nxb1; wb0 = nwb0; wb1 = nwb1; bb0 = nbb0; bb1 = nbb1;
        }
    }

    const size_t pbase = (size_t)blockIdx.x * TDIM + t0;
    *reinterpret_cast<float4*>(partial + pbase)     = make_float4(colacc[0], colacc[1], colacc[2], colacc[3]);
    *reinterpret_cast<float4*>(partial + pbase + 4) = make_float4(colacc[4], colacc[5], colacc[6], colacc[7]);
}

// ---------------------------------------------------------------------------
// K2: colsum[col] = sum over 512 partial rows (32 slices x 16 rows).
// ---------------------------------------------------------------------------
__global__ __launch_bounds__(256) void k2_colsum(
    const float* __restrict__ partial, float* __restrict__ colsum)
{
    const int gid = blockIdx.x * 256 + threadIdx.x;   // 0..65535
    const int col = gid & (TDIM - 1);
    const int slc = gid >> 11;                        // 0..31
    const float* p = partial + (size_t)slc * 16 * TDIM + col;
    float s = 0.0f;
#pragma unroll
    for (int i = 0; i < 16; ++i) s += p[(size_t)i * TDIM];
    atomicAdd(colsum + col, s);
}

// ---------------------------------------------------------------------------
// K3: per-y-block objective partials — NO atomics.
// grid (2, 512) = 1024 blocks = 16 waves/CU; 8 rows/thread, float4 cols.
// ---------------------------------------------------------------------------
#define K3_ROWS 8
__global__ __launch_bounds__(256) void k3_part(
    const float* __restrict__ cum,
    const float* __restrict__ baselines,
    const float* __restrict__ lp,
    const float* __restrict__ colsum,
    float* __restrict__ objpart)
{
    const int c4 = (blockIdx.x * 256 + threadIdx.x) * 4;   // column group
    const int yb = blockIdx.y;                             // 0..511
    const int r0 = yb * K3_ROWS;
    const float inv = 1.0f / (float)BDIM;
    float4 ms = *reinterpret_cast<const float4*>(colsum + c4);
    const float m0 = ms.x * inv, m1 = ms.y * inv, m2 = ms.z * inv, m3 = ms.w * inv;

    float a0 = 0.0f, a1 = 0.0f, a2 = 0.0f, a3 = 0.0f;
    size_t idx = (size_t)r0 * TDIM + c4;
#pragma unroll
    for (int r = 0; r < K3_ROWS; ++r, idx += TDIM) {
        float4 c = *reinterpret_cast<const float4*>(cum + idx);
        float4 b = *reinterpret_cast<const float4*>(baselines + idx);
        float4 l = *reinterpret_cast<const float4*>(lp + idx);
        a0 = fmaf(clip5(c.x - b.x - m0), l.x, a0);
        a1 = fmaf(clip5(c.y - b.y - m1), l.y, a1);
        a2 = fmaf(clip5(c.z - b.z - m2), l.z, a2);
        a3 = fmaf(clip5(c.w - b.w - m3), l.w, a3);
    }
    *reinterpret_cast<float4*>(objpart + (size_t)yb * TDIM + c4) =
        make_float4(a0, a1, a2, a3);
}

// ---------------------------------------------------------------------------
// K4: obj[col] = sum over 512 objpart rows (32 slices x 16 rows) — k2 clone.
// ---------------------------------------------------------------------------
__global__ __launch_bounds__(256) void k4_objsum(
    const float* __restrict__ objpart, float* __restrict__ obj)
{
    const int gid = blockIdx.x * 256 + threadIdx.x;   // 0..65535
    const int col = gid & (TDIM - 1);
    const int slc = gid >> 11;                        // 0..31
    const float* p = objpart + (size_t)slc * 16 * TDIM + col;
    float s = 0.0f;
#pragma unroll
    for (int i = 0; i < 16; ++i) s += p[(size_t)i * TDIM];
    atomicAdd(obj + col, s);
}

extern "C" void kernel_launch(void* const* d_in, const int* in_sizes, int n_in,
                              void* d_out, int out_size, void* d_ws, size_t ws_size,
                              hipStream_t stream) {
    const float* log_probs = (const float*)d_in[0];   // [B,T]
    const float* logits    = (const float*)d_in[1];   // [B,T,1]
    const float* weight    = (const float*)d_in[2];   // [B,T]
    const float* baselines = (const float*)d_in[3];   // [B,T,1]

    float* out = (float*)d_out;
    float* obj = out;            // [T]
    float* cum = out + TDIM;     // [B,T]

    float* partial = (float*)d_ws;                       // [512][2048] = 4 MB
    float* colsum  = partial + (size_t)NBLK * TDIM;      // 2048 floats

    // k1 writes partial (colacc) and zeroes colsum/obj.
    k1_scan<<<NBLK, 256, 0, stream>>>(logits, weight, baselines, cum, partial, colsum, obj);
    // k2 consumes partial -> colsum.
    k2_colsum<<<256, 256, 0, stream>>>(partial, colsum);
    // k3 reuses partial as objpart (k2 finished reading it; stream-ordered).
    k3_part<<<dim3(2, 512), 256, 0, stream>>>(cum, baselines, log_probs, colsum, partial);
    // k4 reduces objpart -> obj.
    k4_objsum<<<256, 256, 0, stream>>>(partial, obj);
}

// Round 8
// 162.027 us; speedup vs baseline: 1.0339x; 1.0339x over previous
//
#include <hip/hip_runtime.h>
#include <math.h>

// Problem constants (match reference).
#define BDIM 4096
#define TDIM 2048
#define NBLK 512          // k1 grid: BDIM / RPB  (partial stays [512][2048] = 4 MB)
#define RPB  8            // rows per k1 block

// gamma powers as exact compile-time folded constants
constexpr double gpow(int e) {
    double r = 1.0;
    for (int i = 0; i < e; ++i) r *= 0.99;
    return r;
}

__device__ __forceinline__ float logsig_fast(float x) {
    // log(sigmoid(x)) = min(x,0) - log(1 + exp(-|x|)); HW transcendentals.
    float z = __expf(-fabsf(x));
    return fminf(x, 0.0f) - __logf(1.0f + z);
}

__device__ __forceinline__ float clip5(float x) {
    return fminf(fmaxf(x, -5.0f), 5.0f);
}

// ---------------------------------------------------------------------------
// K1: per-row reverse discounted scan (c[t] = wr[t] + g*c[t+1]); writes cum
// and per-block column partials.
// 512 THREADS/BLOCK (4 cols/thread, 8 waves) -> 16 waves/CU at 2 blocks/CU.
// Rationale: k1 was pinned at ~43 us across 3 different inner loops; the
// limiter is per-CU streaming throughput at 8 waves/CU (~2 TB/s). Doubling
// resident waves doubles outstanding memory per CU.
// Blocks 0/1 zero colsum/obj (replaces memsets).
// ---------------------------------------------------------------------------
__global__ __launch_bounds__(512) void k1_scan(
    const float* __restrict__ logits,
    const float* __restrict__ weight,
    const float* __restrict__ baselines,
    float* __restrict__ cum_out,
    float* __restrict__ partial,
    float* __restrict__ colsum,
    float* __restrict__ obj)
{
    const int tid  = threadIdx.x;     // 0..511
    const int lane = tid & 63;
    const int wave = tid >> 6;        // 0..7
    const int t0   = tid * 4;         // 4 contiguous columns per thread

    // in-kernel zeroing (k2/k3/k4 are stream-ordered after k1)
    if (blockIdx.x == 0) {
        *reinterpret_cast<float4*>(colsum + t0) = make_float4(0.f, 0.f, 0.f, 0.f);
    }
    if (blockIdx.x == 1) {
        *reinterpret_cast<float4*>(obj + t0) = make_float4(0.f, 0.f, 0.f, 0.f);
    }

    const float G    = 0.99f;
    const float G256 = (float)gpow(256);       // one wave spans 64*4 = 256 cols
    const float LOG2G = -0.014499569695115089f;  // log2(0.99)
    // gamma^(4-k) for k=0..3
    const float gk[4] = {(float)gpow(4), (float)gpow(3), (float)gpow(2), (float)gpow(1)};
    // shuffle-scan factors gamma^(4*2^s), s=0..5
    const float fs[6] = {(float)gpow(4),  (float)gpow(8),  (float)gpow(16),
                         (float)gpow(32), (float)gpow(64), (float)gpow(128)};
    // gamma^((64-lane)*4): distance from this thread's first col to next wave's first col
    const float lane_pow = exp2f((float)((64 - lane) * 4) * LOG2G);

    __shared__ float wsum[2][8];   // [iter parity][wave]

    float colacc[4];
#pragma unroll
    for (int k = 0; k < 4; ++k) colacc[k] = 0.0f;

    const int row0 = blockIdx.x * RPB;
    size_t base = (size_t)row0 * TDIM + t0;

    // preload row 0
    float4 x0 = *reinterpret_cast<const float4*>(logits + base);
    float4 w0 = *reinterpret_cast<const float4*>(weight + base);
    float4 b0 = *reinterpret_cast<const float4*>(baselines + base);

    for (int r = 0; r < RPB; ++r) {
        const size_t nbase = base + TDIM;
        const bool has_next = (r + 1 < RPB);

        float wr[4];
        wr[0] = w0.x * logsig_fast(x0.x); wr[1] = w0.y * logsig_fast(x0.y);
        wr[2] = w0.z * logsig_fast(x0.z); wr[3] = w0.w * logsig_fast(x0.w);

        // prefetch next row: latency hides under the scan chain below
        float4 nx0, nw0, nb0;
        if (has_next) {
            nx0 = *reinterpret_cast<const float4*>(logits + nbase);
            nw0 = *reinterpret_cast<const float4*>(weight + nbase);
            nb0 = *reinterpret_cast<const float4*>(baselines + nbase);
        }

        // local suffix scan over 4 elems: loc[k] = sum_{s>=k} g^(s-k) wr[s]
        float loc[4];
        loc[3] = wr[3];
#pragma unroll
        for (int k = 2; k >= 0; --k) loc[k] = fmaf(G, loc[k + 1], wr[k]);

        // wave-level weighted suffix scan over per-thread totals
        float v = loc[0];
#pragma unroll
        for (int s = 0; s < 6; ++s) {
            const int o = 1 << s;
            float up = __shfl_down(v, (unsigned)o, 64);
            if (lane + o < 64) v = fmaf(fs[s], up, v);
        }

        // cross-wave carry via LDS over 8 waves — ONE barrier per row
        const int buf = r & 1;
        if (lane == 0) wsum[buf][wave] = v;
        __syncthreads();
        const float W1 = wsum[buf][1], W2 = wsum[buf][2], W3 = wsum[buf][3];
        const float W4 = wsum[buf][4], W5 = wsum[buf][5], W6 = wsum[buf][6];
        const float W7 = wsum[buf][7];
        // C_w = suffix carry entering wave w's region from waves > w
        const float C6 = W7;
        const float C5 = fmaf(G256, C6, W6);
        const float C4 = fmaf(G256, C5, W5);
        const float C3 = fmaf(G256, C4, W4);
        const float C2 = fmaf(G256, C3, W3);
        const float C1 = fmaf(G256, C2, W2);
        const float C0 = fmaf(G256, C1, W1);
        const float carry = (wave == 0) ? C0 : (wave == 1) ? C1 : (wave == 2) ? C2 :
                            (wave == 3) ? C3 : (wave == 4) ? C4 : (wave == 5) ? C5 :
                            (wave == 6) ? C6 : 0.0f;

        // full suffix value at this thread's first element
        const float vfull = fmaf(lane_pow, carry, v);
        // cumulative at element t0+4 (tail): next lane's vfull; lane 63 -> carry
        const float vn = __shfl_down(vfull, 1, 64);
        const float tail = (lane == 63) ? carry : vn;

        float c[4];
#pragma unroll
        for (int k = 0; k < 4; ++k) c[k] = fmaf(gk[k], tail, loc[k]);

        *reinterpret_cast<float4*>(cum_out + base) = make_float4(c[0], c[1], c[2], c[3]);

        colacc[0] += c[0] - b0.x; colacc[1] += c[1] - b0.y;
        colacc[2] += c[2] - b0.z; colacc[3] += c[3] - b0.w;

        base = nbase;
        if (has_next) {
            x0 = nx0; w0 = nw0; b0 = nb0;
        }
    }

    const size_t pbase = (size_t)blockIdx.x * TDIM + t0;
    *reinterpret_cast<float4*>(partial + pbase) =
        make_float4(colacc[0], colacc[1], colacc[2], colacc[3]);
}

// ---------------------------------------------------------------------------
// K2: colsum[col] = sum over 512 partial rows (32 slices x 16 rows).
// ---------------------------------------------------------------------------
__global__ __launch_bounds__(256) void k2_colsum(
    const float* __restrict__ partial, float* __restrict__ colsum)
{
    const int gid = blockIdx.x * 256 + threadIdx.x;   // 0..65535
    const int col = gid & (TDIM - 1);
    const int slc = gid >> 11;                        // 0..31
    const float* p = partial + (size_t)slc * 16 * TDIM + col;
    float s = 0.0f;
#pragma unroll
    for (int i = 0; i < 16; ++i) s += p[(size_t)i * TDIM];
    atomicAdd(colsum + col, s);
}

// ---------------------------------------------------------------------------
// K3: per-y-block objective partials — NO atomics.
// grid (4, 512) = 2048 blocks = 32 waves/CU; 8 rows/thread, float2 cols.
// Column-split across blockIdx.x keeps objpart at [512][2048].
// ---------------------------------------------------------------------------
#define K3_ROWS 8
__global__ __launch_bounds__(256) void k3_part(
    const float* __restrict__ cum,
    const float* __restrict__ baselines,
    const float* __restrict__ lp,
    const float* __restrict__ colsum,
    float* __restrict__ objpart)
{
    const int c2 = (blockIdx.x * 256 + threadIdx.x) * 2;   // column pair
    const int yb = blockIdx.y;                             // 0..511
    const int r0 = yb * K3_ROWS;
    const float inv = 1.0f / (float)BDIM;
    float2 ms = *reinterpret_cast<const float2*>(colsum + c2);
    const float m0 = ms.x * inv, m1 = ms.y * inv;

    float a0 = 0.0f, a1 = 0.0f;
    size_t idx = (size_t)r0 * TDIM + c2;
#pragma unroll
    for (int r = 0; r < K3_ROWS; ++r, idx += TDIM) {
        float2 c = *reinterpret_cast<const float2*>(cum + idx);
        float2 b = *reinterpret_cast<const float2*>(baselines + idx);
        float2 l = *reinterpret_cast<const float2*>(lp + idx);
        a0 = fmaf(clip5(c.x - b.x - m0), l.x, a0);
        a1 = fmaf(clip5(c.y - b.y - m1), l.y, a1);
    }
    *reinterpret_cast<float2*>(objpart + (size_t)yb * TDIM + c2) = make_float2(a0, a1);
}

// ---------------------------------------------------------------------------
// K4: obj[col] = sum over 512 objpart rows (32 slices x 16 rows) — k2 clone.
// ---------------------------------------------------------------------------
__global__ __launch_bounds__(256) void k4_objsum(
    const float* __restrict__ objpart, float* __restrict__ obj)
{
    const int gid = blockIdx.x * 256 + threadIdx.x;   // 0..65535
    const int col = gid & (TDIM - 1);
    const int slc = gid >> 11;                        // 0..31
    const float* p = objpart + (size_t)slc * 16 * TDIM + col;
    float s = 0.0f;
#pragma unroll
    for (int i = 0; i < 16; ++i) s += p[(size_t)i * TDIM];
    atomicAdd(obj + col, s);
}

extern "C" void kernel_launch(void* const* d_in, const int* in_sizes, int n_in,
                              void* d_out, int out_size, void* d_ws, size_t ws_size,
                              hipStream_t stream) {
    const float* log_probs = (const float*)d_in[0];   // [B,T]
    const float* logits    = (const float*)d_in[1];   // [B,T,1]
    const float* weight    = (const float*)d_in[2];   // [B,T]
    const float* baselines = (const float*)d_in[3];   // [B,T,1]

    float* out = (float*)d_out;
    float* obj = out;            // [T]
    float* cum = out + TDIM;     // [B,T]

    float* partial = (float*)d_ws;                       // [512][2048] = 4 MB
    float* colsum  = partial + (size_t)NBLK * TDIM;      // 2048 floats

    // k1 writes partial (colacc) and zeroes colsum/obj.
    k1_scan<<<NBLK, 512, 0, stream>>>(logits, weight, baselines, cum, partial, colsum, obj);
    // k2 consumes partial -> colsum.
    k2_colsum<<<256, 256, 0, stream>>>(partial, colsum);
    // k3 reuses partial as objpart (k2 finished reading it; stream-ordered).
    k3_part<<<dim3(4, 512), 256, 0, stream>>>(cum, baselines, log_probs, colsum, partial);
    // k4 reduces objpart -> obj.
    k4_objsum<<<256, 256, 0, stream>>>(partial, obj);
}